// Round 15
// baseline (531.392 us; speedup 1.0000x reference)
//
#include <hip/hip_runtime.h>
#include <cstdint>
#include <cmath>

#define HID 32
#define GATES 96  // 3*HID
#define F 128
#define CHUNK 256

typedef float nfloat2 __attribute__((ext_vector_type(2)));

__device__ inline unsigned f2b(float x) {   // f32 -> bf16 (RNE)
    unsigned u = __float_as_uint(x);
    return (u + 0x7FFFu + ((u >> 16) & 1u)) >> 16;
}
__device__ inline float blo(unsigned u) { return __uint_as_float(u << 16); }
__device__ inline float bhi(unsigned u) { return __uint_as_float(u & 0xFFFF0000u); }

// ws layout (float units): xwh[N*48] (N*96 bf16) | sorted[E*2] | dinv[N] | cnt[N] | off[N] | csum[1024] | bias96[96]
// rank[E] (u32) OVERLAYS xwh: rank dies at k_permute, before k_gemm writes xwh.

// the only atomics: rank[e] = old count (edge's slot in its dst segment)
__global__ __launch_bounds__(256) void k_hist(const int* __restrict__ ei_dst,
                                              unsigned* __restrict__ cnt,
                                              unsigned* __restrict__ rank, int E) {
    int e = blockIdx.x * 256 + threadIdx.x;
    if (e >= E) return;
    rank[e] = atomicAdd(&cnt[ei_dst[e]], 1u);
}

__global__ __launch_bounds__(256) void k_chunksum(const unsigned* __restrict__ cnt,
                                                  unsigned* __restrict__ csum, int N) {
    __shared__ unsigned s[256];
    int i = blockIdx.x * 256 + threadIdx.x;
    s[threadIdx.x] = (i < N) ? cnt[i] : 0u;
    __syncthreads();
    for (int off = 128; off > 0; off >>= 1) {
        if (threadIdx.x < off) s[threadIdx.x] += s[threadIdx.x + off];
        __syncthreads();
    }
    if (threadIdx.x == 0) csum[blockIdx.x] = s[0];
}

// single block: exclusive scan over chunk sums + fill bias96 table
__global__ __launch_bounds__(1024) void k_scanchunks(unsigned* __restrict__ csum, int nc,
        const float* __restrict__ bz, const float* __restrict__ br, const float* __restrict__ bh,
        float* __restrict__ bias96) {
    __shared__ unsigned s[1024];
    int t = threadIdx.x;
    if (t < 96) bias96[t] = (t < 32) ? bz[t] : ((t < 64) ? br[t - 32] : bh[t - 64]);
    unsigned v = (t < nc) ? csum[t] : 0u;
    s[t] = v;
    __syncthreads();
    for (int o = 1; o < 1024; o <<= 1) {
        unsigned x = s[t];
        if (t >= o) x += s[t - o];
        __syncthreads();
        s[t] = x;
        __syncthreads();
    }
    if (t < nc) csum[t] = s[t] - v;   // exclusive
}

__global__ __launch_bounds__(256) void k_scanapply(const unsigned* __restrict__ cnt,
                                                   const unsigned* __restrict__ csum,
                                                   unsigned* __restrict__ off, int N) {
    __shared__ unsigned s[2][256];
    int t = threadIdx.x, i = blockIdx.x * 256 + t;
    unsigned v = (i < N) ? cnt[i] : 0u;
    int cur = 0;
    s[0][t] = v;
    __syncthreads();
    for (int o = 1; o < 256; o <<= 1) {
        unsigned x = s[cur][t];
        if (t >= o) x += s[cur][t - o];
        s[cur ^ 1][t] = x;
        cur ^= 1;
        __syncthreads();
    }
    unsigned excl = s[cur][t] - v + csum[blockIdx.x];
    if (i < N) off[i] = excl;
}

// atomic-free permute: slot = off[d] + rank[e]; payload (src, raw w)
__global__ __launch_bounds__(256) void k_permute(const int* __restrict__ ei,
        const float* __restrict__ w, const unsigned* __restrict__ off,
        const unsigned* __restrict__ rank, float2* __restrict__ sorted, int E) {
    int e = blockIdx.x * 256 + threadIdx.x;
    if (e >= E) return;
    int s = ei[e];
    int d = ei[(size_t)E + e];
    unsigned p = off[d] + rank[e];
    sorted[p] = make_float2(__int_as_float(s), w[e]);
}

// dinv[n] = rsqrt(1 + sum w over CSR segment)
__global__ __launch_bounds__(256) void k_degsum(const unsigned* __restrict__ off,
        const unsigned* __restrict__ cnt, const float2* __restrict__ sorted,
        float* __restrict__ dinv, int N) {
    int l = threadIdx.x & 31;
    int n = blockIdx.x * 8 + (threadIdx.x >> 5);
    if (n >= N) return;
    unsigned base = off[n], len = cnt[n];
    float s = 0.0f;
    for (unsigned i = l; i < len; i += 32) s += sorted[base + i].y;
    #pragma unroll
    for (int o = 16; o >= 1; o >>= 1) s += __shfl_xor(s, o, 32);
    if (l == 0) dinv[n] = rsqrtf(1.0f + s);
}

// xwh[n][c] (bf16) = dinv[n] * (x[n][:] @ [Wz|Wr|Wh][:, c])   -- dinv folded in
#define GR 16
__global__ __launch_bounds__(256) void k_gemm(const float* __restrict__ x,
        const float* __restrict__ Wz, const float* __restrict__ Wr, const float* __restrict__ Wh,
        const float* __restrict__ dinv, unsigned* __restrict__ xwh, int N) {
    __shared__ float Wl[F * GATES];
    __shared__ float xs[GR][F + 1];
    int tid = threadIdx.x;
    for (int i = tid; i < F * GATES; i += 256) {
        int k = i / GATES, c = i % GATES;
        float v;
        if (c < 32)      v = Wz[k * 32 + c];
        else if (c < 64) v = Wr[k * 32 + (c - 32)];
        else             v = Wh[k * 32 + (c - 64)];
        Wl[i] = v;
    }
    int r_local = tid / 16;
    int cb = tid % 16;
    int ntiles = (N + GR - 1) / GR;
    for (int t = blockIdx.x; t < ntiles; t += gridDim.x) {
        int row0 = t * GR;
        __syncthreads();
        for (int i = tid; i < GR * F; i += 256) {
            int r = i / F, k = i % F;
            int g = row0 + r;
            xs[r][k] = (g < N) ? x[(size_t)g * F + k] : 0.0f;
        }
        __syncthreads();
        int grow = row0 + r_local;
        if (grow < N) {
            float acc[6] = {0, 0, 0, 0, 0, 0};
            for (int k = 0; k < F; ++k) {
                float xv = xs[r_local][k];
                const float* wr = &Wl[k * GATES + cb * 6];
                #pragma unroll
                for (int j = 0; j < 6; ++j) acc[j] += xv * wr[j];
            }
            float dv = dinv[grow];
            unsigned* o = xwh + (size_t)grow * 48 + cb * 3;
            o[0] = f2b(dv * acc[0]) | (f2b(dv * acc[1]) << 16);
            o[1] = f2b(dv * acc[2]) | (f2b(dv * acc[3]) << 16);
            o[2] = f2b(dv * acc[4]) | (f2b(dv * acc[5]) << 16);
        }
    }
}

// one 32-lane group per dst node; 8 subgroups of 4 lanes, subgroup g owns edges j = g, g+8, ...
// lane (g, r): 3x dwordx4 loads cover features 24r..24r+23 of the source row.
// 16 edges per wave-iteration through 4 load instructions -> deep MLP.
__global__ __launch_bounds__(256, 8) void k_fused(
        const unsigned* __restrict__ off, const unsigned* __restrict__ cnt,
        const float2* __restrict__ sorted,
        const unsigned* __restrict__ xwh, const float* __restrict__ dinv, const float* __restrict__ Hin,
        const float* __restrict__ bias96,
        const float* __restrict__ Lzw, const float* __restrict__ Lzb,
        const float* __restrict__ Lrw, const float* __restrict__ Lrb,
        const float* __restrict__ Lhw, const float* __restrict__ Lhb,
        const float* __restrict__ linw, const float* __restrict__ linb,
        float* __restrict__ out_probs, float* __restrict__ out_H, int N) {
    __shared__ float g_lds[8][96];
    int tid = threadIdx.x;
    int l = tid & 31;
    int g = l >> 2;             // subgroup 0..7
    int r = l & 3;              // lane-in-subgroup: features 24r..24r+23
    int node = tid >> 5;        // 0..7 within block
    int n = blockIdx.x * 8 + node;
    if (n >= N) return;

    float di = dinv[n];
    float acc[24];
    #pragma unroll
    for (int i = 0; i < 24; ++i) acc[i] = 0.0f;

    unsigned base = off[n], len = cnt[n];
    const nfloat2* mp = (const nfloat2*)sorted + base;
    const uint4* xw4 = (const uint4*)xwh;
    #pragma unroll 2
    for (unsigned j = g; j < len; j += 8) {
        nfloat2 e = mp[j];                  // 4-lane broadcast (8 addrs per group)
        int   s = __float_as_int(e.x);
        float m = e.y;                      // w (dinv[src] folded into xwh rows)
        const uint4* p = xw4 + (size_t)s * 12 + r * 3;
        uint4 ua = p[0], ub = p[1], uc = p[2];
        acc[0]  += m * blo(ua.x); acc[1]  += m * bhi(ua.x);
        acc[2]  += m * blo(ua.y); acc[3]  += m * bhi(ua.y);
        acc[4]  += m * blo(ua.z); acc[5]  += m * bhi(ua.z);
        acc[6]  += m * blo(ua.w); acc[7]  += m * bhi(ua.w);
        acc[8]  += m * blo(ub.x); acc[9]  += m * bhi(ub.x);
        acc[10] += m * blo(ub.y); acc[11] += m * bhi(ub.y);
        acc[12] += m * blo(ub.z); acc[13] += m * bhi(ub.z);
        acc[14] += m * blo(ub.w); acc[15] += m * bhi(ub.w);
        acc[16] += m * blo(uc.x); acc[17] += m * bhi(uc.x);
        acc[18] += m * blo(uc.y); acc[19] += m * bhi(uc.y);
        acc[20] += m * blo(uc.z); acc[21] += m * bhi(uc.z);
        acc[22] += m * blo(uc.w); acc[23] += m * bhi(uc.w);
    }
    // fold across the 8 subgroups (lanes with equal r): xor over bits 2,3,4 of lane id
    #pragma unroll
    for (int i = 0; i < 24; ++i) {
        acc[i] += __shfl_xor(acc[i], 4, 32);
        acc[i] += __shfl_xor(acc[i], 8, 32);
        acc[i] += __shfl_xor(acc[i], 16, 32);
    }
    // epilogue (subgroup 0 only): self-loop + di scale + bias -> LDS
    if (g == 0) {
        const uint4* ps = xw4 + (size_t)n * 12 + r * 3;
        uint4 sa = ps[0], sb = ps[1], sc = ps[2];
        float self[24] = {
            blo(sa.x), bhi(sa.x), blo(sa.y), bhi(sa.y), blo(sa.z), bhi(sa.z), blo(sa.w), bhi(sa.w),
            blo(sb.x), bhi(sb.x), blo(sb.y), bhi(sb.y), blo(sb.z), bhi(sb.z), blo(sb.w), bhi(sb.w),
            blo(sc.x), bhi(sc.x), blo(sc.y), bhi(sc.y), blo(sc.z), bhi(sc.z), blo(sc.w), bhi(sc.w)};
        #pragma unroll
        for (int i = 0; i < 24; ++i) {
            int f = r * 24 + i;
            g_lds[node][f] = di * (acc[i] + self[i]) + bias96[f];
        }
    }
    // intra-wave LDS write->read: program order + lgkmcnt ordering, no barrier needed
    float gz = g_lds[node][l];
    float gr = g_lds[node][32 + l];
    float gh = g_lds[node][64 + l];

    float Hd = Hin[(size_t)n * HID + l];

    float az = Lzb[l], ar = Lrb[l];
    #pragma unroll 4
    for (int k = 0; k < 32; ++k) {
        float gzk = __shfl(gz, k, 32);
        float grk = __shfl(gr, k, 32);
        float Hk  = __shfl(Hd, k, 32);
        az += gzk * Lzw[k * 32 + l] + Hk * Lzw[(32 + k) * 32 + l];
        ar += grk * Lrw[k * 32 + l] + Hk * Lrw[(32 + k) * 32 + l];
    }
    float Z  = 1.0f / (1.0f + __expf(-az));
    float Rg = 1.0f / (1.0f + __expf(-ar));
    float HR = Hd * Rg;
    float ah = Lhb[l];
    #pragma unroll 4
    for (int k = 0; k < 32; ++k) {
        float ghk = __shfl(gh, k, 32);
        float HRk = __shfl(HR, k, 32);
        ah += ghk * Lhw[k * 32 + l] + HRk * Lhw[(32 + k) * 32 + l];
    }
    float Ht = tanhf(ah);
    float Hn = Z * Hd + (1.0f - Z) * Ht;
    float h = fmaxf(Hn, 0.0f);

    float logit = (l < 10) ? linb[l] : -INFINITY;
    #pragma unroll 4
    for (int k = 0; k < 32; ++k) {
        float hk = __shfl(h, k, 32);
        if (l < 10) logit += hk * linw[k * 10 + l];
    }
    float mx = logit;
    #pragma unroll
    for (int o = 8; o >= 1; o >>= 1) mx = fmaxf(mx, __shfl_xor(mx, o, 16));
    float ex = (l < 10) ? __expf(logit - mx) : 0.0f;
    float sum = ex;
    #pragma unroll
    for (int o = 8; o >= 1; o >>= 1) sum += __shfl_xor(sum, o, 16);
    if (l < 10) out_probs[(size_t)n * 10 + l] = ex / sum;
    out_H[(size_t)n * HID + l] = Hd;
}

extern "C" void kernel_launch(void* const* d_in, const int* in_sizes, int n_in,
                              void* d_out, int out_size, void* d_ws, size_t ws_size,
                              hipStream_t stream) {
    const float* x    = (const float*)d_in[0];
    const int*   ei   = (const int*)d_in[1];     // int32, layout [2][E]
    const float* ew   = (const float*)d_in[2];
    const float* H    = (const float*)d_in[3];
    const float* Wz   = (const float*)d_in[4];
    const float* bz   = (const float*)d_in[5];
    const float* Wr   = (const float*)d_in[6];
    const float* br   = (const float*)d_in[7];
    const float* Wh   = (const float*)d_in[8];
    const float* bh   = (const float*)d_in[9];
    const float* Lzw  = (const float*)d_in[10];
    const float* Lzb  = (const float*)d_in[11];
    const float* Lrw  = (const float*)d_in[12];
    const float* Lrb  = (const float*)d_in[13];
    const float* Lhw  = (const float*)d_in[14];
    const float* Lhb  = (const float*)d_in[15];
    const float* linw = (const float*)d_in[16];
    const float* linb = (const float*)d_in[17];

    int N = in_sizes[0] / F;
    int E = in_sizes[2];
    int nchunk = (N + CHUNK - 1) / CHUNK;   // 391 for N=100k (scan supports <=1024)

    float* ws = (float*)d_ws;
    unsigned* xwh    = (unsigned*)ws;                       // N*48 u32 (N*96 bf16)
    float2*   sorted = (float2*)(ws + (size_t)N * 48);
    float*    dinv   = ws + (size_t)N * 48 + (size_t)E * 2;
    unsigned* cnt    = (unsigned*)(dinv + N);
    unsigned* off    = cnt + N;
    unsigned* csum   = off + N;
    float*    bias96 = (float*)(csum + 1024);
    unsigned* rank   = xwh;    // overlay: E u32 (12.8MB) <= N*48 u32 (19.2MB); dead before k_gemm

    float* out_probs = (float*)d_out;
    float* out_H     = (float*)d_out + (size_t)N * 10;

    hipMemsetAsync(cnt, 0, (size_t)N * sizeof(unsigned), stream);
    k_hist<<<(E + 255) / 256, 256, 0, stream>>>(ei + (size_t)E, cnt, rank, E);
    k_chunksum<<<nchunk, 256, 0, stream>>>(cnt, csum, N);
    k_scanchunks<<<1, 1024, 0, stream>>>(csum, nchunk, bz, br, bh, bias96);
    k_scanapply<<<nchunk, 256, 0, stream>>>(cnt, csum, off, N);
    k_permute<<<(E + 255) / 256, 256, 0, stream>>>(ei, ew, off, rank, sorted, E);
    k_degsum<<<(N + 7) / 8, 256, 0, stream>>>(off, cnt, sorted, dinv, N);
    k_gemm<<<2048, 256, 0, stream>>>(x, Wz, Wr, Wh, dinv, xwh, N);
    k_fused<<<(N + 7) / 8, 256, 0, stream>>>(off, cnt, sorted, xwh, dinv, H, bias96,
                                             Lzw, Lzb, Lrw, Lrb, Lhw, Lhb,
                                             linw, linb, out_probs, out_H, N);
}

// Round 16
// 461.243 us; speedup vs baseline: 1.1521x; 1.1521x over previous
//
#include <hip/hip_runtime.h>
#include <cstdint>
#include <cmath>

#define HID 32
#define GATES 96  // 3*HID
#define F 128
#define NB_MAX 512   // coarse buckets (dst>>8), nb = ceil(N/256) = 391 for N=100k
#define CH 4096      // edges per scatter block

typedef float nfloat2 __attribute__((ext_vector_type(2)));

__device__ inline unsigned f2b(float x) {   // f32 -> bf16 (RNE)
    unsigned u = __float_as_uint(x);
    return (u + 0x7FFFu + ((u >> 16) & 1u)) >> 16;
}

// ws layout: xwh[N*48 u32] | sorted[E f2] | bsorted[E f2] | bldst[E u8] | dinv[N] | cnt[N] | off[N] | bCnt[512] | bOff[512] | bPos[512]

// A: coarse histogram, LDS-aggregated (global atomics: <=nb per block)
__global__ __launch_bounds__(256) void k_bcount(const int* __restrict__ ei_dst,
        unsigned* __restrict__ bCnt, int E, int nb) {
    __shared__ unsigned h[NB_MAX];
    for (int i = threadIdx.x; i < NB_MAX; i += 256) h[i] = 0;
    __syncthreads();
    for (int e = blockIdx.x * 256 + threadIdx.x; e < E; e += gridDim.x * 256)
        atomicAdd(&h[ei_dst[e] >> 8], 1u);
    __syncthreads();
    for (int b = threadIdx.x; b < nb; b += 256)
        if (h[b]) atomicAdd(&bCnt[b], h[b]);
}

// B: exclusive scan of bucket counts (single block)
__global__ __launch_bounds__(512) void k_bscan(const unsigned* __restrict__ bCnt,
        unsigned* __restrict__ bOff, unsigned* __restrict__ bPos, int nb) {
    __shared__ unsigned s[512];
    int t = threadIdx.x;
    unsigned v = (t < nb) ? bCnt[t] : 0u;
    s[t] = v;
    __syncthreads();
    for (int o = 1; o < 512; o <<= 1) {
        unsigned x = s[t];
        if (t >= o) x += s[t - o];
        __syncthreads();
        s[t] = x;
        __syncthreads();
    }
    if (t < nb) { unsigned ex = s[t] - v; bOff[t] = ex; bPos[t] = ex; }
}

// C: scatter edges into bucket-major order; per-block range reservation
__global__ __launch_bounds__(256) void k_bscatter(const int* __restrict__ ei,
        const float* __restrict__ w, unsigned* __restrict__ bPos,
        float2* __restrict__ bsorted, unsigned char* __restrict__ bldst, int E) {
    __shared__ unsigned h[NB_MAX], base[NB_MAX];
    int c0 = blockIdx.x * CH;
    int c1 = c0 + CH; if (c1 > E) c1 = E;
    for (int i = threadIdx.x; i < NB_MAX; i += 256) h[i] = 0;
    __syncthreads();
    for (int e = c0 + threadIdx.x; e < c1; e += 256)
        atomicAdd(&h[ei[(size_t)E + e] >> 8], 1u);
    __syncthreads();
    for (int b = threadIdx.x; b < NB_MAX; b += 256) {
        base[b] = h[b] ? atomicAdd(&bPos[b], h[b]) : 0u;
        h[b] = 0;   // reuse as placement counter
    }
    __syncthreads();
    for (int e = c0 + threadIdx.x; e < c1; e += 256) {
        int d = ei[(size_t)E + e];
        int b = d >> 8;
        unsigned r = atomicAdd(&h[b], 1u);
        unsigned slot = base[b] + r;
        bsorted[slot] = make_float2(__int_as_float(ei[e]), w[e]);
        bldst[slot] = (unsigned char)(d & 255);
    }
}

// D: per-bucket fine counting sort (LDS atomics) -> final CSR + cnt/off/dinv
__global__ __launch_bounds__(256) void k_bfine(const float2* __restrict__ bsorted,
        const unsigned char* __restrict__ bldst, const unsigned* __restrict__ bOff,
        float2* __restrict__ sorted, unsigned* __restrict__ cnt, unsigned* __restrict__ off,
        float* __restrict__ dinv, int N, int E, int nb) {
    __shared__ unsigned h[256], h2[256], loc[256];
    __shared__ float ws[256];
    int b = blockIdx.x;
    int t = threadIdx.x;
    unsigned lo = bOff[b];
    unsigned hi = (b + 1 < nb) ? bOff[b + 1] : (unsigned)E;
    h[t] = 0; h2[t] = 0; ws[t] = 0.0f;
    __syncthreads();
    for (unsigned i = lo + t; i < hi; i += 256) {
        int ld = bldst[i];
        atomicAdd(&h[ld], 1u);
        atomicAdd(&ws[ld], bsorted[i].y);
    }
    __syncthreads();
    unsigned v = h[t];
    loc[t] = v;
    __syncthreads();
    for (int o = 1; o < 256; o <<= 1) {
        unsigned x = loc[t];
        if (t >= o) x += loc[t - o];
        __syncthreads();
        loc[t] = x;
        __syncthreads();
    }
    unsigned ex = loc[t] - v;
    __syncthreads();
    loc[t] = ex;
    __syncthreads();
    int d = b * 256 + t;
    if (d < N) {
        cnt[d] = h[t];
        off[d] = lo + loc[t];
        dinv[d] = rsqrtf(1.0f + ws[t]);
    }
    for (unsigned i = lo + t; i < hi; i += 256) {
        int ld = bldst[i];
        unsigned r = atomicAdd(&h2[ld], 1u);
        sorted[lo + loc[ld] + r] = bsorted[i];
    }
}

// xwh[n][c] (bf16) = dinv[n] * (x[n][:] @ [Wz|Wr|Wh][:, c])   -- dinv folded in
#define GR 16
__global__ __launch_bounds__(256) void k_gemm(const float* __restrict__ x,
        const float* __restrict__ Wz, const float* __restrict__ Wr, const float* __restrict__ Wh,
        const float* __restrict__ dinv, unsigned* __restrict__ xwh, int N) {
    __shared__ float Wl[F * GATES];
    __shared__ float xs[GR][F + 1];
    int tid = threadIdx.x;
    for (int i = tid; i < F * GATES; i += 256) {
        int k = i / GATES, c = i % GATES;
        float v;
        if (c < 32)      v = Wz[k * 32 + c];
        else if (c < 64) v = Wr[k * 32 + (c - 32)];
        else             v = Wh[k * 32 + (c - 64)];
        Wl[i] = v;
    }
    int r_local = tid / 16;
    int cb = tid % 16;
    int ntiles = (N + GR - 1) / GR;
    for (int t = blockIdx.x; t < ntiles; t += gridDim.x) {
        int row0 = t * GR;
        __syncthreads();
        for (int i = tid; i < GR * F; i += 256) {
            int r = i / F, k = i % F;
            int g = row0 + r;
            xs[r][k] = (g < N) ? x[(size_t)g * F + k] : 0.0f;
        }
        __syncthreads();
        int grow = row0 + r_local;
        if (grow < N) {
            float acc[6] = {0, 0, 0, 0, 0, 0};
            for (int k = 0; k < F; ++k) {
                float xv = xs[r_local][k];
                const float* wr = &Wl[k * GATES + cb * 6];
                #pragma unroll
                for (int j = 0; j < 6; ++j) acc[j] += xv * wr[j];
            }
            float dv = dinv[grow];
            unsigned* o = xwh + (size_t)grow * 48 + cb * 3;
            o[0] = f2b(dv * acc[0]) | (f2b(dv * acc[1]) << 16);
            o[1] = f2b(dv * acc[2]) | (f2b(dv * acc[3]) << 16);
            o[2] = f2b(dv * acc[4]) | (f2b(dv * acc[5]) << 16);
        }
    }
}

// R14's best k_fused: two 16-lane halves, dual-slot loop, dinv pre-folded into xwh.
__global__ __launch_bounds__(256, 8) void k_fused(
        const unsigned* __restrict__ off, const unsigned* __restrict__ cnt,
        const float2* __restrict__ sorted,
        const unsigned* __restrict__ xwh, const float* __restrict__ dinv, const float* __restrict__ Hin,
        const float* __restrict__ bz, const float* __restrict__ br, const float* __restrict__ bh,
        const float* __restrict__ Lzw, const float* __restrict__ Lzb,
        const float* __restrict__ Lrw, const float* __restrict__ Lrb,
        const float* __restrict__ Lhw, const float* __restrict__ Lhb,
        const float* __restrict__ linw, const float* __restrict__ linb,
        float* __restrict__ out_probs, float* __restrict__ out_H, int N) {
    int tid = threadIdx.x;
    int l = tid & 31;
    int half = l >> 4;
    int q = l & 15;
    int n = blockIdx.x * 8 + (tid >> 5);
    if (n >= N) return;

    float di = dinv[n];
    float acc0 = 0, acc1 = 0, acc2 = 0, acc3 = 0, acc4 = 0, acc5 = 0;

    unsigned base = off[n], len = cnt[n];
    const nfloat2* mp = (const nfloat2*)sorted + base;
    unsigned j = half;
    #pragma unroll 2
    for (; j + 2 < len; j += 4) {
        nfloat2 ea = mp[j];
        nfloat2 eb = mp[j + 2];
        int   sa = __float_as_int(ea.x);
        int   sb = __float_as_int(eb.x);
        float ma = ea.y;
        float mb = eb.y;
        const unsigned* pa = xwh + (size_t)sa * 48 + q * 3;
        const unsigned* pb = xwh + (size_t)sb * 48 + q * 3;
        unsigned a0 = pa[0], a1 = pa[1], a2 = pa[2];
        unsigned b0 = pb[0], b1 = pb[1], b2 = pb[2];
        acc0 += ma * __uint_as_float(a0 << 16);
        acc1 += ma * __uint_as_float(a0 & 0xFFFF0000u);
        acc2 += ma * __uint_as_float(a1 << 16);
        acc3 += ma * __uint_as_float(a1 & 0xFFFF0000u);
        acc4 += ma * __uint_as_float(a2 << 16);
        acc5 += ma * __uint_as_float(a2 & 0xFFFF0000u);
        acc0 += mb * __uint_as_float(b0 << 16);
        acc1 += mb * __uint_as_float(b0 & 0xFFFF0000u);
        acc2 += mb * __uint_as_float(b1 << 16);
        acc3 += mb * __uint_as_float(b1 & 0xFFFF0000u);
        acc4 += mb * __uint_as_float(b2 << 16);
        acc5 += mb * __uint_as_float(b2 & 0xFFFF0000u);
    }
    for (; j < len; j += 2) {
        nfloat2 e = mp[j];
        int   s = __float_as_int(e.x);
        float m = e.y;
        const unsigned* p = xwh + (size_t)s * 48 + q * 3;
        unsigned u0 = p[0], u1 = p[1], u2 = p[2];
        acc0 += m * __uint_as_float(u0 << 16);
        acc1 += m * __uint_as_float(u0 & 0xFFFF0000u);
        acc2 += m * __uint_as_float(u1 << 16);
        acc3 += m * __uint_as_float(u1 & 0xFFFF0000u);
        acc4 += m * __uint_as_float(u2 << 16);
        acc5 += m * __uint_as_float(u2 & 0xFFFF0000u);
    }
    acc0 += __shfl_xor(acc0, 16, 32);
    acc1 += __shfl_xor(acc1, 16, 32);
    acc2 += __shfl_xor(acc2, 16, 32);
    acc3 += __shfl_xor(acc3, 16, 32);
    acc4 += __shfl_xor(acc4, 16, 32);
    acc5 += __shfl_xor(acc5, 16, 32);
    float g0, g1, g2, g3, g4, g5;
    {
        const unsigned* p = xwh + (size_t)n * 48 + q * 3;
        unsigned u0 = p[0], u1 = p[1], u2 = p[2];
        #define BIAS(f) ((f) < 32 ? bz[(f)] : ((f) < 64 ? br[(f) - 32] : bh[(f) - 64]))
        int f = q * 6;
        g0 = di * (acc0 + __uint_as_float(u0 << 16))         + BIAS(f);
        g1 = di * (acc1 + __uint_as_float(u0 & 0xFFFF0000u)) + BIAS(f + 1);
        g2 = di * (acc2 + __uint_as_float(u1 << 16))         + BIAS(f + 2);
        g3 = di * (acc3 + __uint_as_float(u1 & 0xFFFF0000u)) + BIAS(f + 3);
        g4 = di * (acc4 + __uint_as_float(u2 << 16))         + BIAS(f + 4);
        g5 = di * (acc5 + __uint_as_float(u2 & 0xFFFF0000u)) + BIAS(f + 5);
        #undef BIAS
    }
    #define GATHERF(out, fexp) { int ff = (fexp); int mm = ff / 6, ii = ff % 6;            \
        float t0 = __shfl(g0, mm, 32), t1 = __shfl(g1, mm, 32), t2 = __shfl(g2, mm, 32),   \
              t3 = __shfl(g3, mm, 32), t4 = __shfl(g4, mm, 32), t5 = __shfl(g5, mm, 32);   \
        out = ii == 0 ? t0 : ii == 1 ? t1 : ii == 2 ? t2 : ii == 3 ? t3 : ii == 4 ? t4 : t5; }
    float gz, gr, gh;
    GATHERF(gz, l);
    GATHERF(gr, 32 + l);
    GATHERF(gh, 64 + l);
    #undef GATHERF

    float Hd = Hin[(size_t)n * HID + l];

    float az = Lzb[l], ar = Lrb[l];
    #pragma unroll 4
    for (int k = 0; k < 32; ++k) {
        float gzk = __shfl(gz, k, 32);
        float grk = __shfl(gr, k, 32);
        float Hk  = __shfl(Hd, k, 32);
        az += gzk * Lzw[k * 32 + l] + Hk * Lzw[(32 + k) * 32 + l];
        ar += grk * Lrw[k * 32 + l] + Hk * Lrw[(32 + k) * 32 + l];
    }
    float Z  = 1.0f / (1.0f + __expf(-az));
    float Rg = 1.0f / (1.0f + __expf(-ar));
    float HR = Hd * Rg;
    float ah = Lhb[l];
    #pragma unroll 4
    for (int k = 0; k < 32; ++k) {
        float ghk = __shfl(gh, k, 32);
        float HRk = __shfl(HR, k, 32);
        ah += ghk * Lhw[k * 32 + l] + HRk * Lhw[(32 + k) * 32 + l];
    }
    float Ht = tanhf(ah);
    float Hn = Z * Hd + (1.0f - Z) * Ht;
    float h = fmaxf(Hn, 0.0f);

    float logit = (l < 10) ? linb[l] : -INFINITY;
    #pragma unroll 4
    for (int k = 0; k < 32; ++k) {
        float hk = __shfl(h, k, 32);
        if (l < 10) logit += hk * linw[k * 10 + l];
    }
    float mx = logit;
    #pragma unroll
    for (int o = 8; o >= 1; o >>= 1) mx = fmaxf(mx, __shfl_xor(mx, o, 16));
    float ex = (l < 10) ? __expf(logit - mx) : 0.0f;
    float sum = ex;
    #pragma unroll
    for (int o = 8; o >= 1; o >>= 1) sum += __shfl_xor(sum, o, 16);
    if (l < 10) out_probs[(size_t)n * 10 + l] = ex / sum;
    out_H[(size_t)n * HID + l] = Hd;
}

extern "C" void kernel_launch(void* const* d_in, const int* in_sizes, int n_in,
                              void* d_out, int out_size, void* d_ws, size_t ws_size,
                              hipStream_t stream) {
    const float* x    = (const float*)d_in[0];
    const int*   ei   = (const int*)d_in[1];     // int32, layout [2][E]
    const float* ew   = (const float*)d_in[2];
    const float* H    = (const float*)d_in[3];
    const float* Wz   = (const float*)d_in[4];
    const float* bz   = (const float*)d_in[5];
    const float* Wr   = (const float*)d_in[6];
    const float* br   = (const float*)d_in[7];
    const float* Wh   = (const float*)d_in[8];
    const float* bh   = (const float*)d_in[9];
    const float* Lzw  = (const float*)d_in[10];
    const float* Lzb  = (const float*)d_in[11];
    const float* Lrw  = (const float*)d_in[12];
    const float* Lrb  = (const float*)d_in[13];
    const float* Lhw  = (const float*)d_in[14];
    const float* Lhb  = (const float*)d_in[15];
    const float* linw = (const float*)d_in[16];
    const float* linb = (const float*)d_in[17];

    int N = in_sizes[0] / F;
    int E = in_sizes[2];
    int nb = (N + 255) / 256;   // coarse buckets (<=512)

    float* ws = (float*)d_ws;
    unsigned*      xwh     = (unsigned*)ws;                         // N*48 u32
    float2*        sorted  = (float2*)(ws + (size_t)N * 48);        // E float2
    float2*        bsorted = sorted + (size_t)E;                    // E float2
    unsigned char* bldst   = (unsigned char*)(bsorted + (size_t)E); // E bytes
    float*         dinv    = (float*)(bldst + ((size_t)E + 3) / 4 * 4);
    unsigned*      cnt     = (unsigned*)(dinv + N);
    unsigned*      off     = cnt + N;
    unsigned*      bCnt    = off + N;
    unsigned*      bOff    = bCnt + NB_MAX;
    unsigned*      bPos    = bOff + NB_MAX;

    float* out_probs = (float*)d_out;
    float* out_H     = (float*)d_out + (size_t)N * 10;

    hipMemsetAsync(bCnt, 0, NB_MAX * sizeof(unsigned), stream);
    k_bcount<<<1024, 256, 0, stream>>>(ei + (size_t)E, bCnt, E, nb);
    k_bscan<<<1, 512, 0, stream>>>(bCnt, bOff, bPos, nb);
    k_bscatter<<<(E + CH - 1) / CH, 256, 0, stream>>>(ei, ew, bPos, bsorted, bldst, E);
    k_bfine<<<nb, 256, 0, stream>>>(bsorted, bldst, bOff, sorted, cnt, off, dinv, N, E, nb);
    k_gemm<<<2048, 256, 0, stream>>>(x, Wz, Wr, Wh, dinv, xwh, N);
    k_fused<<<(N + 7) / 8, 256, 0, stream>>>(off, cnt, sorted, xwh, dinv, H,
                                             bz, br, bh, Lzw, Lzb, Lrw, Lrb, Lhw, Lhb,
                                             linw, linb, out_probs, out_H, N);
}

// Round 17
// 410.003 us; speedup vs baseline: 1.2961x; 1.1250x over previous
//
#include <hip/hip_runtime.h>
#include <cstdint>
#include <cmath>

#define HID 32
#define GATES 96  // 3*HID
#define F 128
#define NB_MAX 512    // coarse buckets (dst>>8); nb = 391 for N=100k
#define CH 4096       // edges per scatter block
#define STAGE_CAP 9000

typedef float nfloat2 __attribute__((ext_vector_type(2)));

__device__ inline unsigned f2b(float x) {   // f32 -> bf16 (RNE)
    unsigned u = __float_as_uint(x);
    return (u + 0x7FFFu + ((u >> 16) & 1u)) >> 16;
}

// ws: xwh[N*48 u32] | sorted[E f2] | bsorted[E f2] | dinv[N] | cnt[N] | off[N] | bCnt/bOff/bPos[512]

// A: coarse histogram, LDS-aggregated
__global__ __launch_bounds__(256) void k_bcount(const int* __restrict__ ei_dst,
        unsigned* __restrict__ bCnt, int E, int nb) {
    __shared__ unsigned h[NB_MAX];
    for (int i = threadIdx.x; i < NB_MAX; i += 256) h[i] = 0;
    __syncthreads();
    for (int e = blockIdx.x * 256 + threadIdx.x; e < E; e += gridDim.x * 256)
        atomicAdd(&h[((const unsigned*)ei_dst)[e] >> 8], 1u);
    __syncthreads();
    for (int b = threadIdx.x; b < nb; b += 256)
        if (h[b]) atomicAdd(&bCnt[b], h[b]);
}

// B: exclusive scan of bucket counts (single block)
__global__ __launch_bounds__(512) void k_bscan(const unsigned* __restrict__ bCnt,
        unsigned* __restrict__ bOff, unsigned* __restrict__ bPos, int nb) {
    __shared__ unsigned s[512];
    int t = threadIdx.x;
    unsigned v = (t < nb) ? bCnt[t] : 0u;
    s[t] = v;
    __syncthreads();
    for (int o = 1; o < 512; o <<= 1) {
        unsigned x = s[t];
        if (t >= o) x += s[t - o];
        __syncthreads();
        s[t] = x;
        __syncthreads();
    }
    if (t < nb) { unsigned ex = s[t] - v; bOff[t] = ex; bPos[t] = ex; }
}

// C: scatter edges to bucket-major order; payload packs (src | ldst<<24)
__global__ __launch_bounds__(256) void k_bscatter(const int* __restrict__ ei,
        const float* __restrict__ w, unsigned* __restrict__ bPos,
        float2* __restrict__ bsorted, int E) {
    __shared__ unsigned h[NB_MAX], base[NB_MAX];
    int c0 = blockIdx.x * CH;
    int c1 = c0 + CH; if (c1 > E) c1 = E;
    for (int i = threadIdx.x; i < NB_MAX; i += 256) h[i] = 0;
    __syncthreads();
    for (int e = c0 + threadIdx.x; e < c1; e += 256)
        atomicAdd(&h[((const unsigned*)ei)[(size_t)E + e] >> 8], 1u);
    __syncthreads();
    for (int b = threadIdx.x; b < NB_MAX; b += 256) {
        base[b] = h[b] ? atomicAdd(&bPos[b], h[b]) : 0u;
        h[b] = 0;   // reuse as placement counter
    }
    __syncthreads();
    for (int e = c0 + threadIdx.x; e < c1; e += 256) {
        unsigned d = ((const unsigned*)ei)[(size_t)E + e];
        unsigned b = d >> 8;
        unsigned r = atomicAdd(&h[b], 1u);
        unsigned pack = (unsigned)ei[e] | ((d & 255u) << 24);
        bsorted[base[b] + r] = make_float2(__int_as_float((int)pack), w[e]);
    }
}

// D: per-bucket fine counting sort, single global read via LDS staging -> CSR + dinv
__global__ __launch_bounds__(256) void k_bfine(const float2* __restrict__ bsorted,
        const unsigned* __restrict__ bOff,
        float2* __restrict__ sorted, unsigned* __restrict__ cnt, unsigned* __restrict__ off,
        float* __restrict__ dinv, int N, int E, int nb) {
    __shared__ float2 stage[STAGE_CAP];            // 72 KB
    __shared__ unsigned h[256], h2[256], loc[256];
    __shared__ float wsum[256];
    int b = blockIdx.x, t = threadIdx.x;
    unsigned lo = bOff[b];
    unsigned hi = (b + 1 < nb) ? bOff[b + 1] : (unsigned)E;
    unsigned len = hi - lo;
    unsigned stlen = len < STAGE_CAP ? len : STAGE_CAP;
    h[t] = 0; h2[t] = 0; wsum[t] = 0.0f;
    __syncthreads();
    for (unsigned i = t; i < stlen; i += 256) {
        float2 e = bsorted[lo + i];
        stage[i] = e;
        unsigned ld = ((unsigned)__float_as_int(e.x)) >> 24;
        atomicAdd(&h[ld], 1u);
        atomicAdd(&wsum[ld], e.y);
    }
    for (unsigned i = stlen + t; i < len; i += 256) {   // overflow fallback (никогда in practice)
        float2 e = bsorted[lo + i];
        unsigned ld = ((unsigned)__float_as_int(e.x)) >> 24;
        atomicAdd(&h[ld], 1u);
        atomicAdd(&wsum[ld], e.y);
    }
    __syncthreads();
    unsigned v = h[t];
    loc[t] = v;
    __syncthreads();
    for (int o = 1; o < 256; o <<= 1) {
        unsigned x = loc[t];
        if (t >= o) x += loc[t - o];
        __syncthreads();
        loc[t] = x;
        __syncthreads();
    }
    unsigned ex = loc[t] - v;
    __syncthreads();
    loc[t] = ex;
    __syncthreads();
    int d = b * 256 + t;
    if (d < N) {
        cnt[d] = v;
        off[d] = lo + ex;
        dinv[d] = rsqrtf(1.0f + wsum[t]);
    }
    for (unsigned i = t; i < stlen; i += 256) {
        float2 e = stage[i];
        unsigned u = (unsigned)__float_as_int(e.x);
        unsigned ld = u >> 24;
        unsigned r = atomicAdd(&h2[ld], 1u);
        sorted[lo + loc[ld] + r] = make_float2(__int_as_float((int)(u & 0xFFFFFFu)), e.y);
    }
    for (unsigned i = stlen + t; i < len; i += 256) {
        float2 e = bsorted[lo + i];
        unsigned u = (unsigned)__float_as_int(e.x);
        unsigned ld = u >> 24;
        unsigned r = atomicAdd(&h2[ld], 1u);
        sorted[lo + loc[ld] + r] = make_float2(__int_as_float((int)(u & 0xFFFFFFu)), e.y);
    }
}

// xwh[n][c] (bf16) = dinv[n] * (x[n][:] @ [Wz|Wr|Wh][:, c])
#define GR 16
__global__ __launch_bounds__(256) void k_gemm(const float* __restrict__ x,
        const float* __restrict__ Wz, const float* __restrict__ Wr, const float* __restrict__ Wh,
        const float* __restrict__ dinv, unsigned* __restrict__ xwh, int N) {
    __shared__ float Wl[F * GATES];
    __shared__ float xs[GR][F + 1];
    int tid = threadIdx.x;
    for (int i = tid; i < F * GATES; i += 256) {
        int k = i / GATES, c = i % GATES;
        float v;
        if (c < 32)      v = Wz[k * 32 + c];
        else if (c < 64) v = Wr[k * 32 + (c - 32)];
        else             v = Wh[k * 32 + (c - 64)];
        Wl[i] = v;
    }
    int r_local = tid / 16;
    int cb = tid % 16;
    int ntiles = (N + GR - 1) / GR;
    for (int t = blockIdx.x; t < ntiles; t += gridDim.x) {
        int row0 = t * GR;
        __syncthreads();
        for (int i = tid; i < GR * F; i += 256) {
            int r = i / F, k = i % F;
            int g = row0 + r;
            xs[r][k] = (g < N) ? x[(size_t)g * F + k] : 0.0f;
        }
        __syncthreads();
        int grow = row0 + r_local;
        if (grow < N) {
            float acc[6] = {0, 0, 0, 0, 0, 0};
            for (int k = 0; k < F; ++k) {
                float xv = xs[r_local][k];
                const float* wr = &Wl[k * GATES + cb * 6];
                #pragma unroll
                for (int j = 0; j < 6; ++j) acc[j] += xv * wr[j];
            }
            float dv = dinv[grow];
            unsigned* o = xwh + (size_t)grow * 48 + cb * 3;
            o[0] = f2b(dv * acc[0]) | (f2b(dv * acc[1]) << 16);
            o[1] = f2b(dv * acc[2]) | (f2b(dv * acc[3]) << 16);
            o[2] = f2b(dv * acc[4]) | (f2b(dv * acc[5]) << 16);
        }
    }
}

// R14's k_fused (frozen): two 16-lane halves, dual-slot loop, dinv pre-folded into xwh.
__global__ __launch_bounds__(256, 8) void k_fused(
        const unsigned* __restrict__ off, const unsigned* __restrict__ cnt,
        const float2* __restrict__ sorted,
        const unsigned* __restrict__ xwh, const float* __restrict__ dinv, const float* __restrict__ Hin,
        const float* __restrict__ bz, const float* __restrict__ br, const float* __restrict__ bh,
        const float* __restrict__ Lzw, const float* __restrict__ Lzb,
        const float* __restrict__ Lrw, const float* __restrict__ Lrb,
        const float* __restrict__ Lhw, const float* __restrict__ Lhb,
        const float* __restrict__ linw, const float* __restrict__ linb,
        float* __restrict__ out_probs, float* __restrict__ out_H, int N) {
    int tid = threadIdx.x;
    int l = tid & 31;
    int half = l >> 4;
    int q = l & 15;
    int n = blockIdx.x * 8 + (tid >> 5);
    if (n >= N) return;

    float di = dinv[n];
    float acc0 = 0, acc1 = 0, acc2 = 0, acc3 = 0, acc4 = 0, acc5 = 0;

    unsigned base = off[n], len = cnt[n];
    const nfloat2* mp = (const nfloat2*)sorted + base;
    unsigned j = half;
    #pragma unroll 2
    for (; j + 2 < len; j += 4) {
        nfloat2 ea = mp[j];
        nfloat2 eb = mp[j + 2];
        int   sa = __float_as_int(ea.x);
        int   sb = __float_as_int(eb.x);
        float ma = ea.y;
        float mb = eb.y;
        const unsigned* pa = xwh + (size_t)sa * 48 + q * 3;
        const unsigned* pb = xwh + (size_t)sb * 48 + q * 3;
        unsigned a0 = pa[0], a1 = pa[1], a2 = pa[2];
        unsigned b0 = pb[0], b1 = pb[1], b2 = pb[2];
        acc0 += ma * __uint_as_float(a0 << 16);
        acc1 += ma * __uint_as_float(a0 & 0xFFFF0000u);
        acc2 += ma * __uint_as_float(a1 << 16);
        acc3 += ma * __uint_as_float(a1 & 0xFFFF0000u);
        acc4 += ma * __uint_as_float(a2 << 16);
        acc5 += ma * __uint_as_float(a2 & 0xFFFF0000u);
        acc0 += mb * __uint_as_float(b0 << 16);
        acc1 += mb * __uint_as_float(b0 & 0xFFFF0000u);
        acc2 += mb * __uint_as_float(b1 << 16);
        acc3 += mb * __uint_as_float(b1 & 0xFFFF0000u);
        acc4 += mb * __uint_as_float(b2 << 16);
        acc5 += mb * __uint_as_float(b2 & 0xFFFF0000u);
    }
    for (; j < len; j += 2) {
        nfloat2 e = mp[j];
        int   s = __float_as_int(e.x);
        float m = e.y;
        const unsigned* p = xwh + (size_t)s * 48 + q * 3;
        unsigned u0 = p[0], u1 = p[1], u2 = p[2];
        acc0 += m * __uint_as_float(u0 << 16);
        acc1 += m * __uint_as_float(u0 & 0xFFFF0000u);
        acc2 += m * __uint_as_float(u1 << 16);
        acc3 += m * __uint_as_float(u1 & 0xFFFF0000u);
        acc4 += m * __uint_as_float(u2 << 16);
        acc5 += m * __uint_as_float(u2 & 0xFFFF0000u);
    }
    acc0 += __shfl_xor(acc0, 16, 32);
    acc1 += __shfl_xor(acc1, 16, 32);
    acc2 += __shfl_xor(acc2, 16, 32);
    acc3 += __shfl_xor(acc3, 16, 32);
    acc4 += __shfl_xor(acc4, 16, 32);
    acc5 += __shfl_xor(acc5, 16, 32);
    float g0, g1, g2, g3, g4, g5;
    {
        const unsigned* p = xwh + (size_t)n * 48 + q * 3;
        unsigned u0 = p[0], u1 = p[1], u2 = p[2];
        #define BIAS(f) ((f) < 32 ? bz[(f)] : ((f) < 64 ? br[(f) - 32] : bh[(f) - 64]))
        int f = q * 6;
        g0 = di * (acc0 + __uint_as_float(u0 << 16))         + BIAS(f);
        g1 = di * (acc1 + __uint_as_float(u0 & 0xFFFF0000u)) + BIAS(f + 1);
        g2 = di * (acc2 + __uint_as_float(u1 << 16))         + BIAS(f + 2);
        g3 = di * (acc3 + __uint_as_float(u1 & 0xFFFF0000u)) + BIAS(f + 3);
        g4 = di * (acc4 + __uint_as_float(u2 << 16))         + BIAS(f + 4);
        g5 = di * (acc5 + __uint_as_float(u2 & 0xFFFF0000u)) + BIAS(f + 5);
        #undef BIAS
    }
    #define GATHERF(out, fexp) { int ff = (fexp); int mm = ff / 6, ii = ff % 6;            \
        float t0 = __shfl(g0, mm, 32), t1 = __shfl(g1, mm, 32), t2 = __shfl(g2, mm, 32),   \
              t3 = __shfl(g3, mm, 32), t4 = __shfl(g4, mm, 32), t5 = __shfl(g5, mm, 32);   \
        out = ii == 0 ? t0 : ii == 1 ? t1 : ii == 2 ? t2 : ii == 3 ? t3 : ii == 4 ? t4 : t5; }
    float gz, gr, gh;
    GATHERF(gz, l);
    GATHERF(gr, 32 + l);
    GATHERF(gh, 64 + l);
    #undef GATHERF

    float Hd = Hin[(size_t)n * HID + l];

    float az = Lzb[l], ar = Lrb[l];
    #pragma unroll 4
    for (int k = 0; k < 32; ++k) {
        float gzk = __shfl(gz, k, 32);
        float grk = __shfl(gr, k, 32);
        float Hk  = __shfl(Hd, k, 32);
        az += gzk * Lzw[k * 32 + l] + Hk * Lzw[(32 + k) * 32 + l];
        ar += grk * Lrw[k * 32 + l] + Hk * Lrw[(32 + k) * 32 + l];
    }
    float Z  = 1.0f / (1.0f + __expf(-az));
    float Rg = 1.0f / (1.0f + __expf(-ar));
    float HR = Hd * Rg;
    float ah = Lhb[l];
    #pragma unroll 4
    for (int k = 0; k < 32; ++k) {
        float ghk = __shfl(gh, k, 32);
        float HRk = __shfl(HR, k, 32);
        ah += ghk * Lhw[k * 32 + l] + HRk * Lhw[(32 + k) * 32 + l];
    }
    float Ht = tanhf(ah);
    float Hn = Z * Hd + (1.0f - Z) * Ht;
    float h = fmaxf(Hn, 0.0f);

    float logit = (l < 10) ? linb[l] : -INFINITY;
    #pragma unroll 4
    for (int k = 0; k < 32; ++k) {
        float hk = __shfl(h, k, 32);
        if (l < 10) logit += hk * linw[k * 10 + l];
    }
    float mx = logit;
    #pragma unroll
    for (int o = 8; o >= 1; o >>= 1) mx = fmaxf(mx, __shfl_xor(mx, o, 16));
    float ex = (l < 10) ? __expf(logit - mx) : 0.0f;
    float sum = ex;
    #pragma unroll
    for (int o = 8; o >= 1; o >>= 1) sum += __shfl_xor(sum, o, 16);
    if (l < 10) out_probs[(size_t)n * 10 + l] = ex / sum;
    out_H[(size_t)n * HID + l] = Hd;
}

extern "C" void kernel_launch(void* const* d_in, const int* in_sizes, int n_in,
                              void* d_out, int out_size, void* d_ws, size_t ws_size,
                              hipStream_t stream) {
    const float* x    = (const float*)d_in[0];
    const int*   ei   = (const int*)d_in[1];     // int32, layout [2][E]
    const float* ew   = (const float*)d_in[2];
    const float* H    = (const float*)d_in[3];
    const float* Wz   = (const float*)d_in[4];
    const float* bz   = (const float*)d_in[5];
    const float* Wr   = (const float*)d_in[6];
    const float* br   = (const float*)d_in[7];
    const float* Wh   = (const float*)d_in[8];
    const float* bh   = (const float*)d_in[9];
    const float* Lzw  = (const float*)d_in[10];
    const float* Lzb  = (const float*)d_in[11];
    const float* Lrw  = (const float*)d_in[12];
    const float* Lrb  = (const float*)d_in[13];
    const float* Lhw  = (const float*)d_in[14];
    const float* Lhb  = (const float*)d_in[15];
    const float* linw = (const float*)d_in[16];
    const float* linb = (const float*)d_in[17];

    int N = in_sizes[0] / F;
    int E = in_sizes[2];
    int nb = (N + 255) / 256;   // <= 512

    float* ws = (float*)d_ws;
    unsigned* xwh     = (unsigned*)ws;                        // N*48 u32
    float2*   sorted  = (float2*)(ws + (size_t)N * 48);       // E float2
    float2*   bsorted = sorted + (size_t)E;                   // E float2
    float*    dinv    = (float*)(bsorted + (size_t)E);
    unsigned* cnt     = (unsigned*)(dinv + N);
    unsigned* off     = cnt + N;
    unsigned* bCnt    = off + N;
    unsigned* bOff    = bCnt + NB_MAX;
    unsigned* bPos    = bOff + NB_MAX;

    float* out_probs = (float*)d_out;
    float* out_H     = (float*)d_out + (size_t)N * 10;

    hipMemsetAsync(bCnt, 0, NB_MAX * sizeof(unsigned), stream);
    k_bcount<<<512, 256, 0, stream>>>(ei + (size_t)E, bCnt, E, nb);
    k_bscan<<<1, 512, 0, stream>>>(bCnt, bOff, bPos, nb);
    k_bscatter<<<(E + CH - 1) / CH, 256, 0, stream>>>(ei, ew, bPos, bsorted, E);
    k_bfine<<<nb, 256, 0, stream>>>(bsorted, bOff, sorted, cnt, off, dinv, N, E, nb);
    k_gemm<<<2048, 256, 0, stream>>>(x, Wz, Wr, Wh, dinv, xwh, N);
    k_fused<<<(N + 7) / 8, 256, 0, stream>>>(off, cnt, sorted, xwh, dinv, H,
                                             bz, br, bh, Lzw, Lzb, Lrw, Lrb, Lhw, Lhb,
                                             linw, linb, out_probs, out_H, N);
}